// Round 7
// baseline (7959.100 us; speedup 1.0000x reference)
//
#include <hip/hip_runtime.h>
#include <hip/hip_bf16.h>
#include <cstdint>
#include <cstddef>

// LSTM_3624952398014 — R7: R4's fused-tag LLC exchange (1-RT, self-verifying)
// with 4x less poll traffic: JU=64 j-units per block -> 32 blocks x 512 thr,
// W slice (256 gate rows x 640 K) entirely in VGPR A-fragments (2 N-tiles x
// 20 K-chunks = 160 VGPR/thread). Replication traffic = 64*512*4B*(512/JU):
// JU 16 -> 64 made the poll-round volume 4MB -> 1MB (uncongested fabric).
// R6 taught: never split flag from data (store-ack + RMW serialization);
// the tag must ride in the same word as the payload.
// Layer 1 of the reference is dead code; out = relu(h_final(L0)) @ W_out^T + b.

#define B_ 64
#define T_ 2048
#define F_ 128
#define H_ 512

#define NBLK 32
#define NTHR 512
#define ROWS 16
#define JU 64

#define ACT_STRIDE 1280                 // 640 bf16 per act row
#define SMEM_SZ (16 * ACT_STRIDE)       // 20480 B
#define HSLOT (B_ * H_)                 // 32768 tagged u32 per slot

typedef __bf16 bf16;
typedef __bf16 bf16x4 __attribute__((ext_vector_type(4)));
typedef __bf16 bf16x8 __attribute__((ext_vector_type(8)));
typedef float f32x4 __attribute__((ext_vector_type(4)));
typedef unsigned int u32;
typedef u32 u32x2 __attribute__((ext_vector_type(2)));
typedef u32 u32x4 __attribute__((ext_vector_type(4)));

static __device__ __forceinline__ float sigm(float v) {
  return 1.f / (1.f + __expf(-v));
}
static __device__ __forceinline__ float tanh_f(float v) {
  float a = fminf(fabsf(v), 20.f);
  float e = __expf(-2.f * a);
  float t = 1.f - 2.f * e / (1.f + e);
  return copysignf(t, v);
}
static __device__ __forceinline__ u32 bf16bits(float f) {
  bf16 b = (bf16)f;
  unsigned short us;
  __builtin_memcpy(&us, &b, 2);
  return (u32)us;
}

__global__ void __launch_bounds__(NTHR) prep_kernel(u32* hbuf) {
  int idx = blockIdx.x * blockDim.x + threadIdx.x;   // 128*512 = 65536 = 2*HSLOT
  hbuf[idx] = 0u;                                    // both slots: tag 0, h = 0
}

// x [B][T][F] f32  ->  xbf [T][4 rg][16 row][128] bf16
__global__ void __launch_bounds__(256) xconv_kernel(
    const float* __restrict__ x, bf16* __restrict__ xbf) {
  const int b = blockIdx.x;          // 0..63
  const int t0 = blockIdx.y * 256;   // grid.y = 8
  const int f2 = threadIdx.x & 63;   // 2 floats per thread
  const int tq = threadIdx.x >> 6;   // 0..3
  const int rg = b >> 4, row = b & 15;
  for (int i = 0; i < 64; ++i) {
    int t = t0 + i * 4 + tq;
    float2 xv = *(const float2*)(x + ((size_t)b * T_ + t) * F_ + 2 * f2);
    u32 w = bf16bits(xv.x) | (bf16bits(xv.y) << 16);
    *(u32*)((char*)xbf + ((((size_t)t * 4 + rg) * 16 + row) * 128 + 2 * f2) * 2) = w;
  }
}

__global__ void __launch_bounds__(NTHR, 1) lstm_kernel(
    const float* __restrict__ x,
    const float* __restrict__ Wih,
    const float* __restrict__ Whh,
    const float* __restrict__ bih,
    const float* __restrict__ bhh,
    u32* __restrict__ hbuf,        // [2][B_][H_] tagged u32
    float* __restrict__ hf32,      // [B_][H_] final h fp32
    const bf16* __restrict__ xbf)  // [T][4][16][128] bf16 or nullptr
{
  __shared__ __align__(16) char smem[SMEM_SZ];

  const int tid = threadIdx.x;
  const int bid = blockIdx.x;
  const int rg = bid >> 3;          // 0..3
  const int jg = bid & 7;           // 0..7
  const int row0 = rg * ROWS;
  const int j0 = jg * JU;

  const int lane = tid & 63;
  const int wave = tid >> 6;        // 0..7
  const int fr = lane & 15;
  const int kg = lane >> 4;         // 0..3

  // ---- one-time: W slice -> register A-fragments, 2 N-tiles x 20 K-chunks ----
  // Tile tau covers gates (q=fr>>2) x j-local (fr&3) at jbase = j0+8*wave+4*tau.
  bf16x8 wfrag0[20], wfrag1[20];
  #pragma unroll
  for (int tau = 0; tau < 2; ++tau) {
    const int G = (fr >> 2) * H_ + j0 + 8 * wave + 4 * tau + (fr & 3);
    const float* sih = Wih + (size_t)G * F_;
    const float* shh = Whh + (size_t)G * H_;
    #pragma unroll
    for (int kk = 0; kk < 20; ++kk) {
      const float* s = (kk < 4) ? (sih + kk * 32 + kg * 8)
                                : (shh + (kk - 4) * 32 + kg * 8);
      float4 f0 = *(const float4*)s;
      float4 f1 = *(const float4*)(s + 4);
      bf16x8 w = { (bf16)f0.x, (bf16)f0.y, (bf16)f0.z, (bf16)f0.w,
                   (bf16)f1.x, (bf16)f1.y, (bf16)f1.z, (bf16)f1.w };
      if (tau == 0) wfrag0[kk] = w; else wfrag1[kk] = w;
    }
  }

  // per-lane cells (post-transpose): (row row0+fr, j = j0+8*wave+4*tau+kg)
  const int jc0 = j0 + 8 * wave + kg;
  const int jc1 = jc0 + 4;
  const float bi0 = bih[0 * H_ + jc0] + bhh[0 * H_ + jc0];
  const float bf0 = bih[1 * H_ + jc0] + bhh[1 * H_ + jc0];
  const float bg0 = bih[2 * H_ + jc0] + bhh[2 * H_ + jc0];
  const float bo0 = bih[3 * H_ + jc0] + bhh[3 * H_ + jc0];
  const float bi1 = bih[0 * H_ + jc1] + bhh[0 * H_ + jc1];
  const float bf1 = bih[1 * H_ + jc1] + bhh[1 * H_ + jc1];
  const float bg1 = bih[2 * H_ + jc1] + bhh[2 * H_ + jc1];
  const float bo1 = bih[3 * H_ + jc1] + bhh[3 * H_ + jc1];

  // poll/unpack/x ids: thread (prow, pw) owns row prow, 16 j at [16*pw, +16)
  const int prow = tid >> 5;        // 0..15
  const int pw = tid & 31;
  const int swz = (prow & 7) << 4;
  // f32-fallback x staging: float4 at col 4*pw
  const float* xfall = x + (size_t)(row0 + prow) * T_ * F_ + pw * 4;
  const int xwf = prow * ACT_STRIDE + ((8 * pw) ^ swz);

  const char* bbase = smem + fr * ACT_STRIDE;
  const int bmask = (fr & 7) << 4;

  float c0 = 0.f, c1 = 0.f;

#define ISSUE_POLLS() do { \
    asm volatile("global_load_dwordx4 %0, %1, off sc0 sc1"            : "=v"(v0) : "v"(hb)); \
    asm volatile("global_load_dwordx4 %0, %1, off offset:16 sc0 sc1"  : "=v"(v1) : "v"(hb)); \
    asm volatile("global_load_dwordx4 %0, %1, off offset:32 sc0 sc1"  : "=v"(v2) : "v"(hb)); \
    asm volatile("global_load_dwordx4 %0, %1, off offset:48 sc0 sc1"  : "=v"(v3) : "v"(hb)); \
  } while (0)

  for (int t = 0; t < T_; ++t) {
    // ---- stage x_t into LDS x-region [0,256)B per row ----
    if (xbf) {
      u32x2 xv = *(const u32x2*)((const char*)xbf
                  + ((size_t)t * 4 + rg) * 4096 + tid * 8);
      *(u32x2*)(smem + xwf) = xv;
    } else {
      float4 xv = *(const float4*)(xfall + (size_t)t * F_);
      bf16x4 bv = { (bf16)xv.x, (bf16)xv.y, (bf16)xv.z, (bf16)xv.w };
      *(bf16x4*)(smem + xwf) = bv;
    }
    __syncthreads();   // sync1: x ready; prior step fully consumed

    // ---- issue poll loads (64B/thread); x-chunk MFMAs hide the LLC RT ----
    u32x4 v0, v1, v2, v3;
    const u32* hb = hbuf + (size_t)(t & 1) * HSLOT
                  + (size_t)(row0 + prow) * H_ + 16 * pw;
    ISSUE_POLLS();
    __builtin_amdgcn_sched_barrier(0);

    f32x4 a00 = {0.f,0.f,0.f,0.f}, a01 = {0.f,0.f,0.f,0.f};
    f32x4 a02 = {0.f,0.f,0.f,0.f}, a03 = {0.f,0.f,0.f,0.f};
    f32x4 a10 = {0.f,0.f,0.f,0.f}, a11 = {0.f,0.f,0.f,0.f};
    f32x4 a12 = {0.f,0.f,0.f,0.f}, a13 = {0.f,0.f,0.f,0.f};
    {   // x chunks kk = 0..3; one B read feeds both N-tiles
      bf16x8 p0 = *(const bf16x8*)(bbase + ((0 * 64 + kg * 16) ^ bmask));
      a00 = __builtin_amdgcn_mfma_f32_16x16x32_bf16(wfrag0[0], p0, a00, 0, 0, 0);
      a10 = __builtin_amdgcn_mfma_f32_16x16x32_bf16(wfrag1[0], p0, a10, 0, 0, 0);
      bf16x8 p1 = *(const bf16x8*)(bbase + ((1 * 64 + kg * 16) ^ bmask));
      a01 = __builtin_amdgcn_mfma_f32_16x16x32_bf16(wfrag0[1], p1, a01, 0, 0, 0);
      a11 = __builtin_amdgcn_mfma_f32_16x16x32_bf16(wfrag1[1], p1, a11, 0, 0, 0);
      bf16x8 p2 = *(const bf16x8*)(bbase + ((2 * 64 + kg * 16) ^ bmask));
      a02 = __builtin_amdgcn_mfma_f32_16x16x32_bf16(wfrag0[2], p2, a02, 0, 0, 0);
      a12 = __builtin_amdgcn_mfma_f32_16x16x32_bf16(wfrag1[2], p2, a12, 0, 0, 0);
      bf16x8 p3 = *(const bf16x8*)(bbase + ((3 * 64 + kg * 16) ^ bmask));
      a03 = __builtin_amdgcn_mfma_f32_16x16x32_bf16(wfrag0[3], p3, a03, 0, 0, 0);
      a13 = __builtin_amdgcn_mfma_f32_16x16x32_bf16(wfrag1[3], p3, a13, 0, 0, 0);
    }
    __builtin_amdgcn_sched_barrier(0);

    // ---- spin: all 16 tags >= t  <=>  min(words) >= t<<16 (monotone) ----
    {
      const u32 tgt = (u32)t << 16;
      int guard = 0;
      for (;;) {
        asm volatile("s_waitcnt vmcnt(0)" ::: "memory");
        __builtin_amdgcn_sched_barrier(0);   // rule #18: no hoist of checks
        u32 m0 = v0[0] < v0[1] ? v0[0] : v0[1];
        u32 m1 = v0[2] < v0[3] ? v0[2] : v0[3];
        #define MIN4(V) { m0 = m0 < V[0] ? m0 : V[0]; m0 = m0 < V[1] ? m0 : V[1]; \
                          m1 = m1 < V[2] ? m1 : V[2]; m1 = m1 < V[3] ? m1 : V[3]; }
        MIN4(v1) MIN4(v2) MIN4(v3)
        #undef MIN4
        u32 m = m0 < m1 ? m0 : m1;
        if (m >= tgt) break;
        if (++guard > (1 << 22)) break;      // bail to wrong-answer, never hang
        ISSUE_POLLS();
      }
    }

    // ---- unpack 16 payloads -> act LDS h-region (32B per thread) ----
    {
      char* dst = smem + prow * ACT_STRIDE;
      u32x4 w0 = { (v0[0] & 0xffffu) | (v0[1] << 16),
                   (v0[2] & 0xffffu) | (v0[3] << 16),
                   (v1[0] & 0xffffu) | (v1[1] << 16),
                   (v1[2] & 0xffffu) | (v1[3] << 16) };
      u32x4 w1 = { (v2[0] & 0xffffu) | (v2[1] << 16),
                   (v2[2] & 0xffffu) | (v2[3] << 16),
                   (v3[0] & 0xffffu) | (v3[1] << 16),
                   (v3[2] & 0xffffu) | (v3[3] << 16) };
      *(u32x4*)(dst + ((256 + 32 * pw + 0) ^ swz)) = w0;
      *(u32x4*)(dst + ((256 + 32 * pw + 16) ^ swz)) = w1;
    }
    __syncthreads();   // sync2: h region ready

    // ---- h chunks kk = 4..19, 4 accumulator chains per tile ----
    #pragma unroll
    for (int kk = 4; kk < 20; kk += 4) {
      bf16x8 b0 = *(const bf16x8*)(bbase + (((kk + 0) * 64 + kg * 16) ^ bmask));
      a00 = __builtin_amdgcn_mfma_f32_16x16x32_bf16(wfrag0[kk + 0], b0, a00, 0, 0, 0);
      a10 = __builtin_amdgcn_mfma_f32_16x16x32_bf16(wfrag1[kk + 0], b0, a10, 0, 0, 0);
      bf16x8 b1 = *(const bf16x8*)(bbase + (((kk + 1) * 64 + kg * 16) ^ bmask));
      a01 = __builtin_amdgcn_mfma_f32_16x16x32_bf16(wfrag0[kk + 1], b1, a01, 0, 0, 0);
      a11 = __builtin_amdgcn_mfma_f32_16x16x32_bf16(wfrag1[kk + 1], b1, a11, 0, 0, 0);
      bf16x8 b2 = *(const bf16x8*)(bbase + (((kk + 2) * 64 + kg * 16) ^ bmask));
      a02 = __builtin_amdgcn_mfma_f32_16x16x32_bf16(wfrag0[kk + 2], b2, a02, 0, 0, 0);
      a12 = __builtin_amdgcn_mfma_f32_16x16x32_bf16(wfrag1[kk + 2], b2, a12, 0, 0, 0);
      bf16x8 b3 = *(const bf16x8*)(bbase + (((kk + 3) * 64 + kg * 16) ^ bmask));
      a03 = __builtin_amdgcn_mfma_f32_16x16x32_bf16(wfrag0[kk + 3], b3, a03, 0, 0, 0);
      a13 = __builtin_amdgcn_mfma_f32_16x16x32_bf16(wfrag1[kk + 3], b3, a13, 0, 0, 0);
    }
    f32x4 ds0 = (a00 + a01) + (a02 + a03);
    f32x4 ds1 = (a10 + a11) + (a12 + a13);

    u32* slot_out = hbuf + (size_t)((t + 1) & 1) * HSLOT + (size_t)(row0 + fr) * H_;

    // ---- tile 0: 4x4 transpose across kg -> gate math -> tagged store ----
    {
      float d0 = ds0[0], d1 = ds0[1], d2 = ds0[2], d3 = ds0[3];
      float t0 = __shfl_xor((kg & 2) ? d0 : d2, 32, 64);
      float t1 = __shfl_xor((kg & 2) ? d1 : d3, 32, 64);
      float w0 = (kg & 2) ? t0 : d0;
      float w1 = (kg & 2) ? t1 : d1;
      float w2 = (kg & 2) ? d2 : t0;
      float w3 = (kg & 2) ? d3 : t1;
      float t2 = __shfl_xor((kg & 1) ? w0 : w1, 16, 64);
      float t3 = __shfl_xor((kg & 1) ? w2 : w3, 16, 64);
      float gi = (kg & 1) ? t2 : w0;
      float gf = (kg & 1) ? w1 : t2;
      float gg = (kg & 1) ? t3 : w2;
      float go = (kg & 1) ? w3 : t3;
      float iv = sigm(gi + bi0);
      float fv = sigm(gf + bf0);
      float gv = tanh_f(gg + bg0);
      float ov = sigm(go + bo0);
      c0 = fv * c0 + iv * gv;
      float hv = ov * tanh_f(c0);
      u32 val = ((u32)(t + 1) << 16) | bf16bits(hv);
      u32* dstp = slot_out + jc0;
      asm volatile("global_store_dword %0, %1, off sc0 sc1" :: "v"(dstp), "v"(val) : "memory");
      if (t == T_ - 1) hf32[(size_t)(row0 + fr) * H_ + jc0] = hv;
    }
    // ---- tile 1 ----
    {
      float d0 = ds1[0], d1 = ds1[1], d2 = ds1[2], d3 = ds1[3];
      float t0 = __shfl_xor((kg & 2) ? d0 : d2, 32, 64);
      float t1 = __shfl_xor((kg & 2) ? d1 : d3, 32, 64);
      float w0 = (kg & 2) ? t0 : d0;
      float w1 = (kg & 2) ? t1 : d1;
      float w2 = (kg & 2) ? d2 : t0;
      float w3 = (kg & 2) ? d3 : t1;
      float t2 = __shfl_xor((kg & 1) ? w0 : w1, 16, 64);
      float t3 = __shfl_xor((kg & 1) ? w2 : w3, 16, 64);
      float gi = (kg & 1) ? t2 : w0;
      float gf = (kg & 1) ? w1 : t2;
      float gg = (kg & 1) ? t3 : w2;
      float go = (kg & 1) ? w3 : t3;
      float iv = sigm(gi + bi1);
      float fv = sigm(gf + bf1);
      float gv = tanh_f(gg + bg1);
      float ov = sigm(go + bo1);
      c1 = fv * c1 + iv * gv;
      float hv = ov * tanh_f(c1);
      u32 val = ((u32)(t + 1) << 16) | bf16bits(hv);
      u32* dstp = slot_out + jc1;
      asm volatile("global_store_dword %0, %1, off sc0 sc1" :: "v"(dstp), "v"(val) : "memory");
      if (t == T_ - 1) hf32[(size_t)(row0 + fr) * H_ + jc1] = hv;
    }
  }
#undef ISSUE_POLLS
}

__global__ void __launch_bounds__(64) out_kernel(
    const float* __restrict__ h_f32,
    const float* __restrict__ Wout,
    const float* __restrict__ bout,
    float* __restrict__ out)
{
  int b = blockIdx.x;
  int lane = threadIdx.x;
  float a0 = 0.f, a1 = 0.f, a2 = 0.f, a3 = 0.f;
  for (int j = lane; j < H_; j += 64) {
    float hv = fmaxf(h_f32[(size_t)b * H_ + j], 0.f);
    a0 += hv * Wout[0 * H_ + j];
    a1 += hv * Wout[1 * H_ + j];
    a2 += hv * Wout[2 * H_ + j];
    a3 += hv * Wout[3 * H_ + j];
  }
  #pragma unroll
  for (int off = 32; off; off >>= 1) {
    a0 += __shfl_down(a0, off);
    a1 += __shfl_down(a1, off);
    a2 += __shfl_down(a2, off);
    a3 += __shfl_down(a3, off);
  }
  if (lane == 0) {
    out[b * 4 + 0] = a0 + bout[0];
    out[b * 4 + 1] = a1 + bout[1];
    out[b * 4 + 2] = a2 + bout[2];
    out[b * 4 + 3] = a3 + bout[3];
  }
}

extern "C" void kernel_launch(void* const* d_in, const int* in_sizes, int n_in,
                              void* d_out, int out_size, void* d_ws, size_t ws_size,
                              hipStream_t stream) {
  const float* x    = (const float*)d_in[0];
  const float* Wih  = (const float*)d_in[1];
  const float* Whh  = (const float*)d_in[2];
  const float* bih  = (const float*)d_in[3];
  const float* bhh  = (const float*)d_in[4];
  // d_in[5..8] = layer-1 weights: dead code in the reference, unused.
  const float* Wout = (const float*)d_in[9];
  const float* bout = (const float*)d_in[10];

  char* ws = (char*)d_ws;
  u32*   hbuf = (u32*)ws;                    // 262144 B
  float* hf32 = (float*)(ws + 262144);       // 131072 B
  const size_t XBF_OFF = 393216;
  const size_t XBF_SZ = (size_t)T_ * 4 * 16 * 128 * 2;   // 33554432 B
  bf16* xbf = (ws_size >= XBF_OFF + XBF_SZ) ? (bf16*)(ws + XBF_OFF) : nullptr;

  hipLaunchKernelGGL(prep_kernel, dim3(128), dim3(NTHR), 0, stream, hbuf);
  if (xbf)
    hipLaunchKernelGGL(xconv_kernel, dim3(64, 8), dim3(256), 0, stream, x, xbf);

  void* args[] = { (void*)&x, (void*)&Wih, (void*)&Whh, (void*)&bih, (void*)&bhh,
                   (void*)&hbuf, (void*)&hf32, (void*)&xbf };
  hipLaunchCooperativeKernel((void*)lstm_kernel, dim3(NBLK), dim3(NTHR),
                             args, 0, stream);

  hipLaunchKernelGGL(out_kernel, dim3(B_), dim3(64), 0, stream,
                     hf32, Wout, bout, (float*)d_out);
}

// Round 8
// 3924.553 us; speedup vs baseline: 2.0280x; 2.0280x over previous
//
#include <hip/hip_runtime.h>
#include <hip/hip_bf16.h>
#include <cstdint>
#include <cstddef>

// LSTM_3624952398014 — R8: R4 structure + MALL-resident exchange.
// R7 lesson: 1 MFMA tile/wave (80 weight VGPRs), >=128 blocks. R4 counter
// re-read: FETCH 1.18GB / WRITE 525MB => sc0sc1 polls were MISSING the MALL
// (HBM RT ~900cy) and stores were write-through to HBM. Fix: publish h with
// global_atomic_swap (device-scope RMW executes AT the MALL -> line becomes
// MALL-resident+modified, writeback); sc0sc1 polls then hit MALL (~450cy).
// Plus: partial re-poll (reissue only stale vectors), rcp-based gate math,
// global spin budget (never hangs).
// Layer 1 of the reference is dead code; out = relu(h_final(L0)) @ W_out^T + b.

#define B_ 64
#define T_ 2048
#define F_ 128
#define H_ 512

#define NBLK 128
#define NTHR 256

#define ACT_STRIDE 1280                 // 640 bf16 per act row
#define SMEM_SZ (16 * ACT_STRIDE)       // 20480 B
#define HSLOT (B_ * H_)                 // 32768 tagged u32 per slot

typedef __bf16 bf16;
typedef __bf16 bf16x4 __attribute__((ext_vector_type(4)));
typedef __bf16 bf16x8 __attribute__((ext_vector_type(8)));
typedef float f32x4 __attribute__((ext_vector_type(4)));
typedef unsigned int u32;
typedef u32 u32x2 __attribute__((ext_vector_type(2)));
typedef u32 u32x4 __attribute__((ext_vector_type(4)));

static __device__ __forceinline__ float sigm(float v) {
  // rcp-based: bf16-accurate, no IEEE divide sequence on the critical path
  return __builtin_amdgcn_rcpf(1.f + __expf(-v));
}
static __device__ __forceinline__ float tanh_f(float v) {
  float a = fminf(fabsf(v), 20.f);
  float e = __expf(-2.f * a);
  float t = 1.f - 2.f * e * __builtin_amdgcn_rcpf(1.f + e);
  return copysignf(t, v);
}
static __device__ __forceinline__ u32 bf16bits(float f) {
  bf16 b = (bf16)f;
  unsigned short us;
  __builtin_memcpy(&us, &b, 2);
  return (u32)us;
}
static __device__ __forceinline__ u32 min4(u32x4 v) {
  u32 a = v[0] < v[1] ? v[0] : v[1];
  u32 b = v[2] < v[3] ? v[2] : v[3];
  return a < b ? a : b;
}

__global__ void __launch_bounds__(NTHR) prep_kernel(u32* hbuf) {
  int idx = blockIdx.x * blockDim.x + threadIdx.x;   // 256*256 = 65536 = 2*HSLOT
  if (idx < 2 * HSLOT) hbuf[idx] = 0u;               // both slots: tag 0, h = 0
}

// x [B][T][F] f32  ->  xbf [T][4 rg][16 row][128] bf16
__global__ void __launch_bounds__(NTHR) xconv_kernel(
    const float* __restrict__ x, bf16* __restrict__ xbf) {
  const int b = blockIdx.x;          // 0..63
  const int t0 = blockIdx.y * 256;   // grid.y = 8
  const int f2 = threadIdx.x & 63;   // 2 floats per thread
  const int tq = threadIdx.x >> 6;   // 0..3
  const int rg = b >> 4, row = b & 15;
  for (int i = 0; i < 64; ++i) {
    int t = t0 + i * 4 + tq;
    float2 xv = *(const float2*)(x + ((size_t)b * T_ + t) * F_ + 2 * f2);
    u32 w = bf16bits(xv.x) | (bf16bits(xv.y) << 16);
    *(u32*)((char*)xbf + ((((size_t)t * 4 + rg) * 16 + row) * 128 + 2 * f2) * 2) = w;
  }
}

__global__ void __launch_bounds__(NTHR, 1) lstm_kernel(
    const float* __restrict__ x,
    const float* __restrict__ Wih,
    const float* __restrict__ Whh,
    const float* __restrict__ bih,
    const float* __restrict__ bhh,
    u32* __restrict__ hbuf,        // [2][B_][H_] tagged u32
    float* __restrict__ hf32,      // [B_][H_] final h fp32
    const bf16* __restrict__ xbf)  // [T][4][16][128] bf16 or nullptr
{
  __shared__ __align__(16) char smem[SMEM_SZ];

  const int tid = threadIdx.x;
  const int bid = blockIdx.x;
  const int rg = bid >> 5;          // 0..3
  const int jg = bid & 31;          // 0..31
  const int row0 = rg * 16;
  const int j0 = jg * 16;

  const int lane = tid & 63;
  const int wave = tid >> 6;        // 0..3
  const int fr = lane & 15;
  const int kg = lane >> 4;         // 0..3

  // ---- one-time: W slice -> register A-fragments (1 tile/wave, 80 VGPR) ----
  bf16x8 wfrag[20];
  {
    const int G = (fr >> 2) * H_ + j0 + wave * 4 + (fr & 3);
    const float* sih = Wih + (size_t)G * F_;
    const float* shh = Whh + (size_t)G * H_;
    #pragma unroll
    for (int kk = 0; kk < 20; ++kk) {
      const float* s = (kk < 4) ? (sih + kk * 32 + kg * 8)
                                : (shh + (kk - 4) * 32 + kg * 8);
      float4 f0 = *(const float4*)s;
      float4 f1 = *(const float4*)(s + 4);
      bf16x8 w = { (bf16)f0.x, (bf16)f0.y, (bf16)f0.z, (bf16)f0.w,
                   (bf16)f1.x, (bf16)f1.y, (bf16)f1.z, (bf16)f1.w };
      wfrag[kk] = w;
    }
  }

  // per-lane cell (post-transpose): b = row0+fr, j = j0 + wave*4 + kg
  const int jcol = j0 + wave * 4 + kg;
  const float bi_ = bih[0 * H_ + jcol] + bhh[0 * H_ + jcol];
  const float bf_ = bih[1 * H_ + jcol] + bhh[1 * H_ + jcol];
  const float bg_ = bih[2 * H_ + jcol] + bhh[2 * H_ + jcol];
  const float bo_ = bih[3 * H_ + jcol] + bhh[3 * H_ + jcol];

  // poll/unpack ids
  const int prow = tid >> 4;        // 0..15
  const int pw = tid & 15;
  // f32-fallback x staging ids
  const int r0x = tid >> 5;
  const int c40 = tid & 31;
  const float* xp0 = x + (size_t)(row0 + r0x) * T_ * F_ + c40 * 4;
  const float* xp1 = x + (size_t)(row0 + r0x + 8) * T_ * F_ + c40 * 4;
  const int xw0 = r0x * ACT_STRIDE + ((8 * c40) ^ ((r0x & 7) << 4));
  const int xw1 = (r0x + 8) * ACT_STRIDE + ((8 * c40) ^ (((r0x + 8) & 7) << 4));
  // bf16 x staging ids (row = tid>>4, 16B seg = tid&15)
  const int xw = prow * ACT_STRIDE + ((pw * 16) ^ ((prow & 7) << 4));

  const char* bbase = smem + fr * ACT_STRIDE;
  const int bmask = (fr & 7) << 4;

  float c_state = 0.f;
  int budget = 1 << 22;   // global spin budget: worst case ~1s then wrong-answer

  for (int t = 0; t < T_; ++t) {
    // ---- stage x_t into LDS x-region [0,256)B per row ----
    if (xbf) {
      u32x4 xv = *(const u32x4*)((const char*)xbf
                  + ((size_t)t * 4 + rg) * 4096 + tid * 16);
      *(u32x4*)(smem + xw) = xv;
    } else {
      float4 xv0 = *(const float4*)(xp0 + (size_t)t * F_);
      float4 xv1 = *(const float4*)(xp1 + (size_t)t * F_);
      bf16x4 b0 = { (bf16)xv0.x, (bf16)xv0.y, (bf16)xv0.z, (bf16)xv0.w };
      bf16x4 b1 = { (bf16)xv1.x, (bf16)xv1.y, (bf16)xv1.z, (bf16)xv1.w };
      *(bf16x4*)(smem + xw0) = b0;
      *(bf16x4*)(smem + xw1) = b1;
    }
    __syncthreads();   // sync1: x ready; prior step fully consumed

    // ---- issue poll loads; x-chunk MFMAs hide the first round trip ----
    u32x4 v0, v1, v2, v3, v4, v5, v6, v7;
    const u32* hb = hbuf + (size_t)(t & 1) * HSLOT + (size_t)(row0 + prow) * H_ + 4 * pw;
    asm volatile("global_load_dwordx4 %0, %1, off sc0 sc1"              : "=v"(v0) : "v"(hb));
    asm volatile("global_load_dwordx4 %0, %1, off offset:256 sc0 sc1"   : "=v"(v1) : "v"(hb));
    asm volatile("global_load_dwordx4 %0, %1, off offset:512 sc0 sc1"   : "=v"(v2) : "v"(hb));
    asm volatile("global_load_dwordx4 %0, %1, off offset:768 sc0 sc1"   : "=v"(v3) : "v"(hb));
    asm volatile("global_load_dwordx4 %0, %1, off offset:1024 sc0 sc1"  : "=v"(v4) : "v"(hb));
    asm volatile("global_load_dwordx4 %0, %1, off offset:1280 sc0 sc1"  : "=v"(v5) : "v"(hb));
    asm volatile("global_load_dwordx4 %0, %1, off offset:1536 sc0 sc1"  : "=v"(v6) : "v"(hb));
    asm volatile("global_load_dwordx4 %0, %1, off offset:1792 sc0 sc1"  : "=v"(v7) : "v"(hb));
    __builtin_amdgcn_sched_barrier(0);

    f32x4 a0 = {0.f, 0.f, 0.f, 0.f}, a1 = {0.f, 0.f, 0.f, 0.f};
    f32x4 a2 = {0.f, 0.f, 0.f, 0.f}, a3 = {0.f, 0.f, 0.f, 0.f};
    {
      bf16x8 p0 = *(const bf16x8*)(bbase + ((0 * 64 + kg * 16) ^ bmask));
      a0 = __builtin_amdgcn_mfma_f32_16x16x32_bf16(wfrag[0], p0, a0, 0, 0, 0);
      bf16x8 p1 = *(const bf16x8*)(bbase + ((1 * 64 + kg * 16) ^ bmask));
      a1 = __builtin_amdgcn_mfma_f32_16x16x32_bf16(wfrag[1], p1, a1, 0, 0, 0);
      bf16x8 p2 = *(const bf16x8*)(bbase + ((2 * 64 + kg * 16) ^ bmask));
      a2 = __builtin_amdgcn_mfma_f32_16x16x32_bf16(wfrag[2], p2, a2, 0, 0, 0);
      bf16x8 p3 = *(const bf16x8*)(bbase + ((3 * 64 + kg * 16) ^ bmask));
      a3 = __builtin_amdgcn_mfma_f32_16x16x32_bf16(wfrag[3], p3, a3, 0, 0, 0);
    }
    __builtin_amdgcn_sched_barrier(0);

    // ---- spin: partial re-poll — reissue only stale vectors ----
    {
      const u32 tgt = (u32)t << 16;
      for (;;) {
        asm volatile("s_waitcnt vmcnt(0)" ::: "memory");
        __builtin_amdgcn_sched_barrier(0);   // rule #18: no hoist of checks
        u32 need = 0;
        if (min4(v0) < tgt) need |= 1u;
        if (min4(v1) < tgt) need |= 2u;
        if (min4(v2) < tgt) need |= 4u;
        if (min4(v3) < tgt) need |= 8u;
        if (min4(v4) < tgt) need |= 16u;
        if (min4(v5) < tgt) need |= 32u;
        if (min4(v6) < tgt) need |= 64u;
        if (min4(v7) < tgt) need |= 128u;
        if (!need) break;
        if (--budget < 0) break;             // bail to wrong-answer, never hang
        if (need & 1u)   asm volatile("global_load_dwordx4 %0, %1, off sc0 sc1"             : "=v"(v0) : "v"(hb));
        if (need & 2u)   asm volatile("global_load_dwordx4 %0, %1, off offset:256 sc0 sc1"  : "=v"(v1) : "v"(hb));
        if (need & 4u)   asm volatile("global_load_dwordx4 %0, %1, off offset:512 sc0 sc1"  : "=v"(v2) : "v"(hb));
        if (need & 8u)   asm volatile("global_load_dwordx4 %0, %1, off offset:768 sc0 sc1"  : "=v"(v3) : "v"(hb));
        if (need & 16u)  asm volatile("global_load_dwordx4 %0, %1, off offset:1024 sc0 sc1" : "=v"(v4) : "v"(hb));
        if (need & 32u)  asm volatile("global_load_dwordx4 %0, %1, off offset:1280 sc0 sc1" : "=v"(v5) : "v"(hb));
        if (need & 64u)  asm volatile("global_load_dwordx4 %0, %1, off offset:1536 sc0 sc1" : "=v"(v6) : "v"(hb));
        if (need & 128u) asm volatile("global_load_dwordx4 %0, %1, off offset:1792 sc0 sc1" : "=v"(v7) : "v"(hb));
      }
    }

    // ---- unpack payloads -> act LDS h-region (contiguous 8B per thread) ----
    {
      char* dst = smem + prow * ACT_STRIDE;
      const int swz = (prow & 7) << 4;
      #define UNPACK(i, V)                                                  \
        {                                                                   \
          u32 w0 = (V[0] & 0xffffu) | (V[1] << 16);                         \
          u32 w1 = (V[2] & 0xffffu) | (V[3] << 16);                         \
          u32x2 wp = { w0, w1 };                                            \
          *(u32x2*)(dst + ((256 + 128 * (i) + 8 * pw) ^ swz)) = wp;         \
        }
      UNPACK(0, v0) UNPACK(1, v1) UNPACK(2, v2) UNPACK(3, v3)
      UNPACK(4, v4) UNPACK(5, v5) UNPACK(6, v6) UNPACK(7, v7)
      #undef UNPACK
    }
    __syncthreads();   // sync2: h region ready

    // ---- h chunks kk = 4..19 across 4 accumulator chains ----
    #pragma unroll
    for (int kk = 4; kk < 20; kk += 4) {
      bf16x8 b0 = *(const bf16x8*)(bbase + (((kk + 0) * 64 + kg * 16) ^ bmask));
      a0 = __builtin_amdgcn_mfma_f32_16x16x32_bf16(wfrag[kk + 0], b0, a0, 0, 0, 0);
      bf16x8 b1 = *(const bf16x8*)(bbase + (((kk + 1) * 64 + kg * 16) ^ bmask));
      a1 = __builtin_amdgcn_mfma_f32_16x16x32_bf16(wfrag[kk + 1], b1, a1, 0, 0, 0);
      bf16x8 b2 = *(const bf16x8*)(bbase + (((kk + 2) * 64 + kg * 16) ^ bmask));
      a2 = __builtin_amdgcn_mfma_f32_16x16x32_bf16(wfrag[kk + 2], b2, a2, 0, 0, 0);
      bf16x8 b3 = *(const bf16x8*)(bbase + (((kk + 3) * 64 + kg * 16) ^ bmask));
      a3 = __builtin_amdgcn_mfma_f32_16x16x32_bf16(wfrag[kk + 3], b3, a3, 0, 0, 0);
    }
    f32x4 dsum = (a0 + a1) + (a2 + a3);

    // ---- 4x4 transpose across kg groups -> lane holds 4 gate types ----
    float d0 = dsum[0], d1 = dsum[1], d2 = dsum[2], d3 = dsum[3];
    float t0 = __shfl_xor((kg & 2) ? d0 : d2, 32, 64);
    float t1 = __shfl_xor((kg & 2) ? d1 : d3, 32, 64);
    float w0 = (kg & 2) ? t0 : d0;
    float w1 = (kg & 2) ? t1 : d1;
    float w2 = (kg & 2) ? d2 : t0;
    float w3 = (kg & 2) ? d3 : t1;
    float t2 = __shfl_xor((kg & 1) ? w0 : w1, 16, 64);
    float t3 = __shfl_xor((kg & 1) ? w2 : w3, 16, 64);
    float gi = (kg & 1) ? t2 : w0;
    float gf = (kg & 1) ? w1 : t2;
    float gg = (kg & 1) ? t3 : w2;
    float go = (kg & 1) ? w3 : t3;

    // ---- gate math + state update (1 cell per lane) ----
    float iv = sigm(gi + bi_);
    float fv = sigm(gf + bf_);
    float gv = tanh_f(gg + bg_);
    float ov = sigm(go + bo_);
    c_state = fv * c_state + iv * gv;
    float hv = ov * tanh_f(c_state);

    // ---- publish: atomic swap executes AT the MALL (line stays resident) ----
    u32 val = ((u32)(t + 1) << 16) | bf16bits(hv);
    u32* dstp = hbuf + (size_t)((t + 1) & 1) * HSLOT + (size_t)(row0 + fr) * H_ + jcol;
    asm volatile("global_atomic_swap %0, %1, off" :: "v"(dstp), "v"(val) : "memory");

    if (t == T_ - 1) hf32[(size_t)(row0 + fr) * H_ + jcol] = hv;
  }
}

__global__ void __launch_bounds__(64) out_kernel(
    const float* __restrict__ h_f32,
    const float* __restrict__ Wout,
    const float* __restrict__ bout,
    float* __restrict__ out)
{
  int b = blockIdx.x;
  int lane = threadIdx.x;
  float a0 = 0.f, a1 = 0.f, a2 = 0.f, a3 = 0.f;
  for (int j = lane; j < H_; j += 64) {
    float hv = fmaxf(h_f32[(size_t)b * H_ + j], 0.f);
    a0 += hv * Wout[0 * H_ + j];
    a1 += hv * Wout[1 * H_ + j];
    a2 += hv * Wout[2 * H_ + j];
    a3 += hv * Wout[3 * H_ + j];
  }
  #pragma unroll
  for (int off = 32; off; off >>= 1) {
    a0 += __shfl_down(a0, off);
    a1 += __shfl_down(a1, off);
    a2 += __shfl_down(a2, off);
    a3 += __shfl_down(a3, off);
  }
  if (lane == 0) {
    out[b * 4 + 0] = a0 + bout[0];
    out[b * 4 + 1] = a1 + bout[1];
    out[b * 4 + 2] = a2 + bout[2];
    out[b * 4 + 3] = a3 + bout[3];
  }
}

extern "C" void kernel_launch(void* const* d_in, const int* in_sizes, int n_in,
                              void* d_out, int out_size, void* d_ws, size_t ws_size,
                              hipStream_t stream) {
  const float* x    = (const float*)d_in[0];
  const float* Wih  = (const float*)d_in[1];
  const float* Whh  = (const float*)d_in[2];
  const float* bih  = (const float*)d_in[3];
  const float* bhh  = (const float*)d_in[4];
  // d_in[5..8] = layer-1 weights: dead code in the reference, unused.
  const float* Wout = (const float*)d_in[9];
  const float* bout = (const float*)d_in[10];

  char* ws = (char*)d_ws;
  u32*   hbuf = (u32*)ws;                    // 262144 B
  float* hf32 = (float*)(ws + 262144);       // 131072 B
  const size_t XBF_OFF = 393216;
  const size_t XBF_SZ = (size_t)T_ * 4 * 16 * 128 * 2;   // 33554432 B
  bf16* xbf = (ws_size >= XBF_OFF + XBF_SZ) ? (bf16*)(ws + XBF_OFF) : nullptr;

  hipLaunchKernelGGL(prep_kernel, dim3(256), dim3(NTHR), 0, stream, hbuf);
  if (xbf)
    hipLaunchKernelGGL(xconv_kernel, dim3(64, 8), dim3(NTHR), 0, stream, x, xbf);

  void* args[] = { (void*)&x, (void*)&Wih, (void*)&Whh, (void*)&bih, (void*)&bhh,
                   (void*)&hbuf, (void*)&hf32, (void*)&xbf };
  hipLaunchCooperativeKernel((void*)lstm_kernel, dim3(NBLK), dim3(NTHR),
                             args, 0, stream);

  hipLaunchKernelGGL(out_kernel, dim3(B_), dim3(64), 0, stream,
                     hf32, Wout, bout, (float*)d_out);
}